// Round 1
// baseline (525.179 us; speedup 1.0000x reference)
//
#include <hip/hip_runtime.h>

// PILayer: out[e,h] = sum_c basis[e,c] * ( (([prop[i];prop[j]] @ W1 + b1) @ W2 + b2) @ W3 )[h*8+c]
// E=800000, C=32, hidden 32/32, basis 8.  Pure fp32 VALU kernel (no fp32 MFMA on CDNA4).
// Thread = edge. Weights read via wave-uniform indices -> compiler promotes to s_load
// (scalar cache), so weight traffic costs no VALU/LDS cycles; v_fmac takes SGPR operand.

constexpr int N_EDGES = 800000;
constexpr int H       = 32;    // N_CHANNEL == hidden sizes
constexpr int NB      = 8;     // N_BASIS
constexpr int DOUT    = 256;   // H * NB

__device__ __forceinline__ float dot8(const float (&u)[8], const float4& b0, const float4& b1) {
    float a;
    a = u[0] * b0.x;
    a = fmaf(u[1], b0.y, a);
    a = fmaf(u[2], b0.z, a);
    a = fmaf(u[3], b0.w, a);
    a = fmaf(u[4], b1.x, a);
    a = fmaf(u[5], b1.y, a);
    a = fmaf(u[6], b1.z, a);
    a = fmaf(u[7], b1.w, a);
    return a;
}

__global__ __launch_bounds__(256) void pilayer_f32(
    const float* __restrict__ prop,
    const int*   __restrict__ idx_i,
    const int*   __restrict__ idx_j,
    const float* __restrict__ basis,
    const float* __restrict__ W1,
    const float* __restrict__ b1,
    const float* __restrict__ W2,
    const float* __restrict__ b2,
    const float* __restrict__ W3,
    float*       __restrict__ out)
{
    const int e = blockIdx.x * 256 + threadIdx.x;   // grid is exact: 3125*256 == 800000

    const int i = idx_i[e];
    const int j = idx_j[e];

    const float4* __restrict__ prop4  = reinterpret_cast<const float4*>(prop);
    const float4* __restrict__ basis4 = reinterpret_cast<const float4*>(basis);
    float4*       __restrict__ out4   = reinterpret_cast<float4*>(out);

    // ---------- stage 1 : y1 = [prop[i] ; prop[j]] @ W1 + b1  (64->32) ----------
    float y1[H];
    #pragma unroll
    for (int m = 0; m < H; ++m) y1[m] = b1[m];

    #pragma unroll 1
    for (int q = 0; q < 8; ++q) {                 // rows k = 4q .. 4q+3 (i half)
        const float4 x4 = prop4[i * 8 + q];
        const float* w  = W1 + (4 * q) * H;
        #pragma unroll
        for (int m = 0; m < H; ++m) {
            float a = y1[m];
            a = fmaf(x4.x, w[0 * H + m], a);
            a = fmaf(x4.y, w[1 * H + m], a);
            a = fmaf(x4.z, w[2 * H + m], a);
            a = fmaf(x4.w, w[3 * H + m], a);
            y1[m] = a;
        }
    }
    #pragma unroll 1
    for (int q = 0; q < 8; ++q) {                 // rows k = 32+4q .. 32+4q+3 (j half)
        const float4 x4 = prop4[j * 8 + q];
        const float* w  = W1 + (32 + 4 * q) * H;
        #pragma unroll
        for (int m = 0; m < H; ++m) {
            float a = y1[m];
            a = fmaf(x4.x, w[0 * H + m], a);
            a = fmaf(x4.y, w[1 * H + m], a);
            a = fmaf(x4.z, w[2 * H + m], a);
            a = fmaf(x4.w, w[3 * H + m], a);
            y1[m] = a;
        }
    }

    // ---------- stage 2 : y2 = y1 @ W2 + b2  (32->32), fully unrolled ----------
    float y2[H];
    #pragma unroll
    for (int m = 0; m < H; ++m) y2[m] = b2[m];
    #pragma unroll
    for (int k = 0; k < H; ++k) {
        const float yk = y1[k];
        const float* w = W2 + k * H;
        #pragma unroll
        for (int m = 0; m < H; ++m)
            y2[m] = fmaf(yk, w[m], y2[m]);
    }

    // ---------- stage 3 : out[h] = sum_c basis[c] * (y2 @ W3)[h*8+c] ----------
    // computed as u[h][c] = sum_k y2[k]*W3[k, h*8+c], then out[h] = <u[h], basis>
    const float4 bs0 = basis4[e * 2 + 0];
    const float4 bs1 = basis4[e * 2 + 1];

    #pragma unroll 1
    for (int hq = 0; hq < 8; ++hq) {              // 4 output channels per iteration
        float u[4][8];
        #pragma unroll
        for (int hh = 0; hh < 4; ++hh)
            #pragma unroll
            for (int c = 0; c < 8; ++c) u[hh][c] = 0.f;

        const float* wbase = W3 + hq * 32;        // W3[k, hq*32 + (hh*8+c)], contiguous 128B per k
        #pragma unroll
        for (int k = 0; k < H; ++k) {
            const float yk = y2[k];
            const float* w = wbase + k * DOUT;
            #pragma unroll
            for (int hh = 0; hh < 4; ++hh) {
                #pragma unroll
                for (int c = 0; c < 8; ++c)
                    u[hh][c] = fmaf(yk, w[hh * 8 + c], u[hh][c]);
            }
        }

        float4 r;
        r.x = dot8(u[0], bs0, bs1);
        r.y = dot8(u[1], bs0, bs1);
        r.z = dot8(u[2], bs0, bs1);
        r.w = dot8(u[3], bs0, bs1);
        out4[e * 8 + hq] = r;
    }
}

extern "C" void kernel_launch(void* const* d_in, const int* in_sizes, int n_in,
                              void* d_out, int out_size, void* d_ws, size_t ws_size,
                              hipStream_t stream) {
    const float* prop  = (const float*)d_in[0];
    const int*   idx_i = (const int*)d_in[1];
    const int*   idx_j = (const int*)d_in[2];
    const float* basis = (const float*)d_in[3];
    const float* W1    = (const float*)d_in[4];
    const float* b1    = (const float*)d_in[5];
    const float* W2    = (const float*)d_in[6];
    const float* b2    = (const float*)d_in[7];
    const float* W3    = (const float*)d_in[8];
    float*       outp  = (float*)d_out;

    dim3 grid(N_EDGES / 256);   // 3125, exact — no tail
    pilayer_f32<<<grid, dim3(256), 0, stream>>>(prop, idx_i, idx_j, basis,
                                                W1, b1, W2, b2, W3, outp);
}